// Round 5
// baseline (102.970 us; speedup 1.0000x reference)
//
#include <hip/hip_runtime.h>

#define NDIM 80
#define NB 6400            // batches; also elements per batch matrix
#define LDM 84             // padded row stride (floats): 336B, 16B-aligned,
                           // bank-balanced for per-lane row-strided b128 reads
#define TOL 0.01f

// One WAVE per batch (64-thread blocks) => no __syncthreads anywhere:
// no vmcnt(0) drains, no convoy across waves. Lane l owns row l (and row
// 64+l for l<16). All reductions via shfl; av broadcast via LDS (same-wave
// lgkmcnt ordering only).
__global__ __launch_bounds__(64, 1) void fused_power_kernel(
    const float* __restrict__ x,
    const float* __restrict__ r_zeros,
    const float* __restrict__ r_const,
    const float* __restrict__ weights_t,
    const float* __restrict__ weights_r,
    float* __restrict__ contrib)
{
    __shared__ __align__(16) float Ms[NDIM * LDM];  // 26880 B
    __shared__ __align__(16) float av[NDIM];        // raw (unnormalized) vector

    const int l = threadIdx.x;       // lane 0..63
    const int b = blockIdx.x;
    const size_t base = (size_t)b * NB;

    // Uniform epilogue operands (scalar loads), issued early.
    const int i_idx = b / NDIM;
    const float rc_diag = r_const[base + (size_t)i_idx * (NDIM + 1)]; // [i,j,i,i]
    const float xw = x[b] * weights_t[b];

    // ---- Stage M = rc + wr*rz into LDS (padded rows). ----
    const float4* rc4 = reinterpret_cast<const float4*>(r_const + base);
    const float4* rz4 = reinterpret_cast<const float4*>(r_zeros + base);
    const float4* wr4 = reinterpret_cast<const float4*>(weights_r + base);
    float4* Ms4 = reinterpret_cast<float4*>(Ms);

    float4 c[25];                    // 25-deep prefetch: forces load MLP
    #pragma unroll
    for (int u = 0; u < 25; ++u) c[u] = rc4[u * 64 + l];
    #pragma unroll
    for (int u = 0; u < 25; ++u) {
        const float4 a = rz4[u * 64 + l];
        const float4 w = wr4[u * 64 + l];
        float4 m;
        m.x = fmaf(w.x, a.x, c[u].x);
        m.y = fmaf(w.y, a.y, c[u].y);
        m.z = fmaf(w.z, a.z, c[u].z);
        m.w = fmaf(w.w, a.w, c[u].w);
        const int f  = u * 64 + l;   // float4 index in batch (20 per row)
        const int i  = f / 20;       // row
        const int jq = f - i * 20;   // float4 col
        Ms4[i * (LDM / 4) + jq] = m;
    }
    av[l] = 1.0f;
    if (l < 16) av[64 + l] = 1.0f;

    // ---- Power iteration, barrier-free. ----
    const int r1 = 64 + (l & 15);                    // second row (valid l<16)
    const float4* Mr0 = reinterpret_cast<const float4*>(&Ms[l * LDM]);
    const float4* Mr1 = reinterpret_cast<const float4*>(&Ms[r1 * LDM]);
    const float4* av4 = reinterpret_cast<const float4*>(av);
    const bool has2 = (l < 16);

    float p0_prev = 1.0f, p1_prev = 1.0f;
    float n2 = (float)NDIM;
    float ev_prev = 1e30f;
    float p0 = 0.f, p1 = 0.f;

    for (int n = 1; n <= 101; ++n) {
        const float inv = rsqrtf(n2);              // 1/||av||
        // p = M * (av*inv): two accumulator chains per row
        float a0a = 0.f, a0b = 0.f, a1a = 0.f, a1b = 0.f;
        #pragma unroll
        for (int kc = 0; kc < 20; ++kc) {
            const float4 vv = av4[kc];             // broadcast (conflict-free)
            const float4 m0 = Mr0[kc];
            const float4 m1 = Mr1[kc];
            a0a = fmaf(m0.x, vv.x, fmaf(m0.y, vv.y, a0a));
            a0b = fmaf(m0.z, vv.z, fmaf(m0.w, vv.w, a0b));
            a1a = fmaf(m1.x, vv.x, fmaf(m1.y, vv.y, a1a));
            a1b = fmaf(m1.z, vv.z, fmaf(m1.w, vv.w, a1b));
        }
        p0 = (a0a + a0b) * inv;
        p1 = (a1a + a1b) * inv;

        // Fused dual reduction: s2 = ||p||^2, sd = v_prev . p  (= ev_{n-1})
        float s2 = p0 * p0;
        float sd = (p0_prev * inv) * p0;
        if (has2) {
            s2 = fmaf(p1, p1, s2);
            sd = fmaf(p1_prev * inv, p1, sd);
        }
        #pragma unroll
        for (int mk = 1; mk < 64; mk <<= 1) {
            s2 += __shfl_xor(s2, mk);
            sd += __shfl_xor(sd, mk);
        }
        // freeze v = v_{n-1} (p_prev) on convergence or iteration cap
        if (n == 101 || fabsf(sd - ev_prev) < TOL) break;
        ev_prev = sd;
        n2 = s2;
        av[l] = p0;
        if (has2) av[r1] = p1;
        p0_prev = p0;
        p1_prev = p1;
    }

    // contrib[b][k] = v[k]/v[i] * xw * rc_diag ; normalization cancels in ratio
    const float denom = av[i_idx];                 // raw p_prev[i]
    const float scale = xw * rc_diag / denom;
    const size_t ob = (size_t)b * NDIM;
    contrib[ob + l] = p0_prev * scale;
    if (has2) contrib[ob + 64 + l] = p1_prev * scale;
}

// out[k] = sum_b contrib[b][k]; fixed-order tree -> deterministic.
__global__ __launch_bounds__(256) void reduce_kernel(
    const float* __restrict__ contrib,
    float* __restrict__ out)
{
    __shared__ float s[256];
    const int k = blockIdx.x;
    const int t = threadIdx.x;
    float acc = 0.f;
    for (int b = t; b < NB; b += 256)
        acc += contrib[(size_t)b * NDIM + k];
    s[t] = acc;
    __syncthreads();
    for (int o = 128; o > 0; o >>= 1) {
        if (t < o) s[t] += s[t + o];
        __syncthreads();
    }
    if (t == 0) out[k] = s[0];
}

extern "C" void kernel_launch(void* const* d_in, const int* in_sizes, int n_in,
                              void* d_out, int out_size, void* d_ws, size_t ws_size,
                              hipStream_t stream) {
    const float* x  = (const float*)d_in[0];   // (80,80)
    const float* rz = (const float*)d_in[1];   // (80,80,80,80)
    const float* rc = (const float*)d_in[2];   // (80,80,80,80)
    const float* wt = (const float*)d_in[3];   // (80,80)
    const float* wr = (const float*)d_in[4];   // (80,80,80,80)
    float* out = (float*)d_out;                // (80,)

    float* contrib = (float*)d_ws;             // 6400*80 floats = 2 MB

    hipLaunchKernelGGL(fused_power_kernel, dim3(NB), dim3(64), 0, stream,
                       x, rz, rc, wt, wr, contrib);
    hipLaunchKernelGGL(reduce_kernel, dim3(NDIM), dim3(256), 0, stream,
                       contrib, out);
}

// Round 6
// 101.510 us; speedup vs baseline: 1.0144x; 1.0144x over previous
//
#include <hip/hip_runtime.h>

#define NDIM 80
#define NB (NDIM * NDIM)   // 6400 batches; also elements per batch matrix
#define TOL 0.01f
#define MAXIT 101          // it 0 = prologue (v0, ev0); 1..100 = reference steps

typedef const __attribute__((address_space(1))) void* gas_ptr;
typedef __attribute__((address_space(3))) void* las_ptr;

// One block per batch b = i*80+j.
// r_const -> LDS directly (async global_load_lds, fire-and-forget).
// r_zeros/weights_r -> registers via lane-consecutive dwordx4, ALL TEN loads
// in flight (launch_bounds(320,5) -> ~102 VGPR budget; R4's (320,8) choked
// this path at 28 VGPRs, serializing the reg loads into dependent latency
// chains). LDS 26.3 KB; occupancy 4 blocks/CU = 20 waves.
__global__ __launch_bounds__(320, 5) void fused_power_kernel(
    const float* __restrict__ x,
    const float* __restrict__ r_zeros,
    const float* __restrict__ r_const,
    const float* __restrict__ weights_t,
    const float* __restrict__ weights_r,
    float* __restrict__ contrib)
{
    __shared__ float Ms[NB];    // staged r_const, becomes M in place (25.6 KB)
    __shared__ float v[NDIM];
    __shared__ float av[NDIM];
    __shared__ float red[2];
    __shared__ float sscale;

    const int t    = threadIdx.x;
    const int wv   = t >> 6;     // wave 0..4
    const int lane = t & 63;
    const int b    = blockIdx.x;
    const size_t base = (size_t)b * NB;

    // Async: 25 x 1KB chunks of r_const -> Ms (5 per wave, never stalls issue).
    #pragma unroll
    for (int c = 0; c < 5; ++c) {
        const int foff = (wv * 5 + c) * 256;   // float offset of this 1KB chunk
        __builtin_amdgcn_global_load_lds((gas_ptr)(r_const + base + foff + lane * 4),
                                         (las_ptr)&Ms[foff], 16, 0, 0);
    }

    // rz & wr: 10 coalesced dwordx4, all issued before any use (full MLP).
    float4 a0, a1, a2, a3, a4, w0, w1, w2, w3, w4;
    {
        const float4* rz4 = reinterpret_cast<const float4*>(r_zeros + base);
        const float4* wr4 = reinterpret_cast<const float4*>(weights_r + base);
        a0 = rz4[t];           a1 = rz4[t + 320];     a2 = rz4[t + 640];
        a3 = rz4[t + 960];     a4 = rz4[t + 1280];
        w0 = wr4[t];           w1 = wr4[t + 320];     w2 = wr4[t + 640];
        w3 = wr4[t + 960];     w4 = wr4[t + 1280];
    }
    float4 prod[5];
    prod[0].x = w0.x * a0.x; prod[0].y = w0.y * a0.y; prod[0].z = w0.z * a0.z; prod[0].w = w0.w * a0.w;
    prod[1].x = w1.x * a1.x; prod[1].y = w1.y * a1.y; prod[1].z = w1.z * a1.z; prod[1].w = w1.w * a1.w;
    prod[2].x = w2.x * a2.x; prod[2].y = w2.y * a2.y; prod[2].z = w2.z * a2.z; prod[2].w = w2.w * a2.w;
    prod[3].x = w3.x * a3.x; prod[3].y = w3.y * a3.y; prod[3].z = w3.z * a3.z; prod[3].w = w3.w * a3.w;
    prod[4].x = w4.x * a4.x; prod[4].y = w4.y * a4.y; prod[4].z = w4.z * a4.z; prod[4].w = w4.w * a4.w;

    if (t < NDIM) av[t] = 1.0f;   // seed: av = ones, ||av||^2 = 80
    __syncthreads();              // drains vmcnt(0): rc in LDS, prods ready

    // M = rc + wr*rz, in place. b128 RMW, conflict-free.
    #pragma unroll
    for (int u = 0; u < 5; ++u) {
        float4* p4 = reinterpret_cast<float4*>(&Ms[4 * (t + 320 * u)]);
        float4 cc = *p4;
        cc.x += prod[u].x;
        cc.y += prod[u].y;
        cc.z += prod[u].z;
        cc.w += prod[u].w;
        *p4 = cc;
    }
    float n2 = (float)NDIM;
    float ev = 1e30f;             // prologue never "converges"
    __syncthreads();

    const int r  = t >> 2;        // row 0..79
    const int q  = t & 3;         // column quarter
    const int vq = q * 20;
    const float4* Mr4 = reinterpret_cast<const float4*>(&Ms[r * NDIM + vq]);
    const float4* vv4 = reinterpret_cast<const float4*>(&v[vq]);

    for (int it = 0; it < MAXIT; ++it) {
        // v = av / ||av||
        const float inv = rsqrtf(n2);
        if (t < NDIM) v[t] = av[t] * inv;
        __syncthreads();                       // v ready

        // av = M v : 5x ds_read_b128 (M) + 5x b128 broadcast (v), 20 FMA.
        float p = 0.f;
        #pragma unroll
        for (int u = 0; u < 5; ++u) {
            const float4 mm = Mr4[u];
            const float4 xv = vv4[u];
            p = fmaf(mm.x, xv.x, p);
            p = fmaf(mm.y, xv.y, p);
            p = fmaf(mm.z, xv.z, p);
            p = fmaf(mm.w, xv.w, p);
        }
        p += __shfl_xor(p, 1);
        p += __shfl_xor(p, 2);
        if (q == 0) av[r] = p;
        __syncthreads();                       // av ready

        // Fused dual reduction: n2' = ||av||^2, dot = v.av (wave 0 only)
        if (t < 64) {
            float a_0 = av[t], v_0 = v[t];
            float s2 = a_0 * a_0;
            float sd = v_0 * a_0;
            if (t < 16) {
                float a_1 = av[t + 64], v_1 = v[t + 64];
                s2 = fmaf(a_1, a_1, s2);
                sd = fmaf(v_1, a_1, sd);
            }
            #pragma unroll
            for (int o = 32; o > 0; o >>= 1) {
                s2 += __shfl_down(s2, o);
                sd += __shfl_down(sd, o);
            }
            if (t == 0) { red[0] = s2; red[1] = sd; }
        }
        __syncthreads();                       // red ready
        n2 = red[0];
        const float evn = red[1];
        if (fabsf(ev - evn) < TOL) break;      // uniform across block
        ev = evn;
    }

    // contrib[b][k] = v[k] * x[b]*wt[b]*rc[i,j,i,i] / v[i]
    if (t == 0) {
        const int i_idx = b / NDIM;
        const float rc_diag = r_const[base + (size_t)i_idx * NDIM + i_idx];
        sscale = x[b] * weights_t[b] * rc_diag / v[i_idx];
    }
    __syncthreads();
    if (t < NDIM) contrib[(size_t)b * NDIM + t] = v[t] * sscale;
}

// out[k] = sum_b contrib[b][k]; fixed-order tree -> deterministic.
__global__ __launch_bounds__(256) void reduce_kernel(
    const float* __restrict__ contrib,
    float* __restrict__ out)
{
    __shared__ float s[256];
    const int k = blockIdx.x;
    const int t = threadIdx.x;
    float acc = 0.f;
    for (int b = t; b < NB; b += 256)
        acc += contrib[(size_t)b * NDIM + k];
    s[t] = acc;
    __syncthreads();
    for (int o = 128; o > 0; o >>= 1) {
        if (t < o) s[t] += s[t + o];
        __syncthreads();
    }
    if (t == 0) out[k] = s[0];
}

extern "C" void kernel_launch(void* const* d_in, const int* in_sizes, int n_in,
                              void* d_out, int out_size, void* d_ws, size_t ws_size,
                              hipStream_t stream) {
    const float* x  = (const float*)d_in[0];   // (80,80)
    const float* rz = (const float*)d_in[1];   // (80,80,80,80)
    const float* rc = (const float*)d_in[2];   // (80,80,80,80)
    const float* wt = (const float*)d_in[3];   // (80,80)
    const float* wr = (const float*)d_in[4];   // (80,80,80,80)
    float* out = (float*)d_out;                // (80,)

    float* contrib = (float*)d_ws;             // 6400*80 floats = 2 MB

    hipLaunchKernelGGL(fused_power_kernel, dim3(NB), dim3(320), 0, stream,
                       x, rz, rc, wt, wr, contrib);
    hipLaunchKernelGGL(reduce_kernel, dim3(NDIM), dim3(256), 0, stream,
                       contrib, out);
}